// Round 10
// baseline (509.671 us; speedup 1.0000x reference)
//
#include <hip/hip_runtime.h>
#include <hip/hip_bf16.h>
#include <math.h>

using bf16 = __hip_bfloat16;
typedef short s16x8 __attribute__((ext_vector_type(8)));
typedef short s16x4 __attribute__((ext_vector_type(4)));
typedef float f32x4 __attribute__((ext_vector_type(4)));

#define DIM_C   2048
#define NHEADS  16
#define HEADD   128
#define SEQT    512
#define NBATCH  16
#define MROWS   (NBATCH*SEQT)   // 8192
#define QKVN    (3*DIM_C)       // 6144
#define QKN     (2*DIM_C)       // 4096 (q,k only; v goes straight to vt)

static __device__ __forceinline__ float bf2f(bf16 v){ return __bfloat162float(v); }

// async global->LDS, 16B per lane; LDS dest = wave-uniform base + lane*16
static __device__ __forceinline__ void gl16(const void* g, void* l){
    __builtin_amdgcn_global_load_lds(
        reinterpret_cast<__attribute__((address_space(1))) void*>(
            (unsigned long long)g),
        reinterpret_cast<__attribute__((address_space(3))) void*>(
            (unsigned long long)l),
        16, 0, 0);
}

// ---------------- convert fp32 -> bf16, 8 elts/thread ----------------
__global__ void k_cvt(const float* __restrict__ in, bf16* __restrict__ out, int n){
    size_t i = ((size_t)blockIdx.x*blockDim.x + threadIdx.x)*8;
    if (i >= (size_t)n) return;
    float4 a = *(const float4*)(in+i);
    float4 b = *(const float4*)(in+i+4);
    union { bf16 o[8]; s16x8 v; } u;
    u.o[0]=__float2bfloat16(a.x); u.o[1]=__float2bfloat16(a.y);
    u.o[2]=__float2bfloat16(a.z); u.o[3]=__float2bfloat16(a.w);
    u.o[4]=__float2bfloat16(b.x); u.o[5]=__float2bfloat16(b.y);
    u.o[6]=__float2bfloat16(b.z); u.o[7]=__float2bfloat16(b.w);
    *(s16x8*)(out+i) = u.v;
}

// ---------------- transpose + convert: in fp32 [R][C] -> out bf16 [C][R] ----
__global__ void k_transpose_cvt(const float* __restrict__ in, bf16* __restrict__ out,
                                int R, int C){
    __shared__ float tile[32][33];
    int c0 = blockIdx.x*32, r0 = blockIdx.y*32;
    int tx = threadIdx.x, ty = threadIdx.y;           // block (32,8)
    #pragma unroll
    for(int i=0;i<4;i++)
        tile[ty+8*i][tx] = in[(size_t)(r0+ty+8*i)*C + c0+tx];
    __syncthreads();
    #pragma unroll
    for(int i=0;i<4;i++)
        out[(size_t)(c0+ty+8*i)*R + r0+tx] = __float2bfloat16(tile[tx][ty+8*i]);
}

// ---------------- bf16 GEMM 256x256 tile, 4-phase, strength-reduced --------
// Core K-loop = R7-v4 EXACTLY (unchanged: schedule, ledger, addressing).
// New: MODE-templated epilogue.
//  MODE 0: plain store to C[row*N+col]   (GEMM2, float out)
//  MODE 1: QKV mode (GEMM1):
//    colbase<4096 -> q/k: RoPE fused on first 16 dims of each head
//      (rope lanes: nf==0, wn even, hd=l16<16; partner via shfl_xor 8:
//       lo: x1*c - x2*s, hi: x2*c + x1*s, t=row&511, i=l16&7), store to
//      qk[row*QKN+col] (stride 4096).
//    colbase>=4096 -> V: write transposed to vt[bh][d][t]; per (mf,nf) the
//      4 acc values are 4 consecutive t for one d -> one 8B packed store.
static __device__ __forceinline__ void store_c(bf16* p, float v){ *p = __float2bfloat16(v); }
static __device__ __forceinline__ void store_c(float* p, float v){ *p = v; }

#define BAR()   __builtin_amdgcn_s_barrier()
#define SCHED() __builtin_amdgcn_sched_barrier(0)
#define LGKM0() asm volatile("s_waitcnt lgkmcnt(0)" ::: "memory")
#define VM6()   asm volatile("s_waitcnt vmcnt(6)"   ::: "memory")
#define VM0()   asm volatile("s_waitcnt vmcnt(0)"   ::: "memory")

template<typename OutT, int MODE>
__global__ __launch_bounds__(512, 2) void k_gemm256(const bf16* __restrict__ A,
                                                    const bf16* __restrict__ Bt,
                                                    OutT* __restrict__ C,
                                                    bf16* __restrict__ vt,
                                                    int M, int N, int K){
    __shared__ __align__(16) bf16 AS[2][2][128*64];
    __shared__ __align__(16) bf16 BS[2][2][128*64];
    const int tid = threadIdx.x;
    const int wave = tid>>6, lane = tid&63, quad = lane>>4, l16 = lane&15;
    const int wm = wave>>2, wn = wave&3;

    // bijective XCD swizzle (grid % 8 == 0 for both GEMMs here)
    const int nbx = gridDim.x;
    const int nwg = gridDim.x*gridDim.y;
    int bid = blockIdx.y*nbx + blockIdx.x;
    int swz = (bid&7)*(nwg>>3) + (bid>>3);
    int by = swz / nbx, bx = swz - by*nbx;
    const size_t rowbase = (size_t)by * 256;
    const size_t colbase = (size_t)bx * 256;
    const int NT = K>>6;

    f32x4 acc[8][4];
    #pragma unroll
    for(int i=0;i<8;i++)
        #pragma unroll
        for(int j=0;j<4;j++) acc[i][j] = (f32x4)(0.f);

    // ---- stage decode (once): per i in {0,1} a chunk id, inverse swizzle ----
    int cb0 = wave*64,        cc0 = cb0 + lane;
    int cb1 = 512 + wave*64,  cc1 = cb1 + lane;
    int ri0 = cc0>>3, gg0 = (cc0&7)^(ri0&7);
    int ri1 = cc1>>3, gg1 = (cc1&7)^(ri1&7);
    // rolling global pointers (element units); advanced +=128 per tile-pair
    const bf16* pA0[2];  const bf16* pA1[2];
    const bf16* pB0[2];  const bf16* pB1[2];
    pA0[0] = A  + (rowbase + (size_t)(((ri0>>6)<<7) + (ri0&63)))*(size_t)K + gg0*8;
    pA0[1] = A  + (rowbase + (size_t)(((ri1>>6)<<7) + (ri1&63)))*(size_t)K + gg1*8;
    pA1[0] = pA0[0] + (size_t)64*K;  pA1[1] = pA0[1] + (size_t)64*K;
    pB0[0] = Bt + (colbase + (size_t)(((ri0>>5)<<6) + (ri0&31)))*(size_t)K + gg0*8;
    pB0[1] = Bt + (colbase + (size_t)(((ri1>>5)<<6) + (ri1&31)))*(size_t)K + gg1*8;
    pB1[0] = pB0[0] + (size_t)32*K;  pB1[1] = pB0[1] + (size_t)32*K;
    const int dE0 = cb0*8, dE1 = cb1*8;      // LDS dest element offsets (plane-local)

    // ---- ds_read base offsets (thread-invariant, element units) ----
    const int x7 = l16 & 7;
    int aB[2], bB[2];
    #pragma unroll
    for(int kc=0;kc<2;kc++){
        int ch = ((kc*4+quad) ^ x7) << 3;
        aB[kc] = (wm*64 + l16)*64 + ch;
        bB[kc] = (wn*32 + l16)*64 + ch;
    }

    s16x8 af[4][2], bf0[2][2], bf1[2][2];

#define READ_AF(BUF,MH) do{ _Pragma("unroll")                                    \
    for(int kc_=0;kc_<2;kc_++){ _Pragma("unroll")                                \
        for(int mi_=0;mi_<4;mi_++)                                               \
            af[mi_][kc_] = *(const s16x8*)(&AS[BUF][MH][aB[kc_] + mi_*1024]); } }while(0)
#define READ_BF(BUF,NH,DST) do{ _Pragma("unroll")                                \
    for(int kc_=0;kc_<2;kc_++){ _Pragma("unroll")                                \
        for(int nj_=0;nj_<2;nj_++)                                               \
            DST[nj_][kc_] = *(const s16x8*)(&BS[BUF][NH][bB[kc_] + nj_*1024]); } }while(0)
// kc-outer: dependent same-acc MFMAs 8 apart
#define MFMA16(BFR,MH,NH) do{ _Pragma("unroll")                                  \
    for(int kc_=0;kc_<2;kc_++){ _Pragma("unroll")                                \
        for(int mi_=0;mi_<4;mi_++){ _Pragma("unroll")                            \
            for(int nj_=0;nj_<2;nj_++)                                           \
                acc[(MH)*4+mi_][(NH)*2+nj_] =                                    \
                    __builtin_amdgcn_mfma_f32_16x16x32_bf16(                     \
                        af[mi_][kc_], BFR[nj_][kc_],                             \
                        acc[(MH)*4+mi_][(NH)*2+nj_], 0,0,0); } } }while(0)

#define STG_A0(BUF,OFF) do{ gl16(pA0[0]+(OFF), &AS[BUF][0][dE0]);                \
                            gl16(pA0[1]+(OFF), &AS[BUF][0][dE1]); }while(0)
#define STG_A1(BUF,OFF) do{ gl16(pA1[0]+(OFF), &AS[BUF][1][dE0]);                \
                            gl16(pA1[1]+(OFF), &AS[BUF][1][dE1]); }while(0)
#define STG_B0(BUF,OFF) do{ gl16(pB0[0]+(OFF), &BS[BUF][0][dE0]);                \
                            gl16(pB0[1]+(OFF), &BS[BUF][0][dE1]); }while(0)
#define STG_B1(BUF,OFF) do{ gl16(pB1[0]+(OFF), &BS[BUF][1][dE0]);                \
                            gl16(pB1[1]+(OFF), &BS[BUF][1][dE1]); }while(0)

#define TILE(BUF,O1,O2,GA1,GR)                                                   \
    do{                                                                          \
        /* P1 */                                                                 \
        if (GA1) STG_A1(BUF^1, O1);                                              \
        READ_AF(BUF,0); READ_BF(BUF,0,bf0);                                      \
        BAR(); LGKM0(); SCHED();                                                 \
        __builtin_amdgcn_s_setprio(1);  MFMA16(bf0,0,0);                         \
        __builtin_amdgcn_s_setprio(0);                                           \
        BAR(); SCHED();                                                          \
        /* P2 */                                                                 \
        if (GR) STG_A0(BUF,O2);                                                  \
        READ_BF(BUF,1,bf1);                                                      \
        BAR(); LGKM0(); SCHED();                                                 \
        __builtin_amdgcn_s_setprio(1);  MFMA16(bf1,0,1);                         \
        __builtin_amdgcn_s_setprio(0);                                           \
        BAR(); SCHED();                                                          \
        /* P3 */                                                                 \
        if (GR) STG_B0(BUF,O2);                                                  \
        READ_AF(BUF,1);                                                          \
        BAR(); LGKM0(); SCHED();                                                 \
        __builtin_amdgcn_s_setprio(1);  MFMA16(bf0,1,0);                         \
        __builtin_amdgcn_s_setprio(0);                                           \
        BAR(); SCHED();                                                          \
        /* P4 */                                                                 \
        if (GR){ STG_B1(BUF,O2); VM6(); } else { VM0(); }                        \
        BAR(); SCHED();                                                          \
        __builtin_amdgcn_s_setprio(1);  MFMA16(bf1,1,1);                         \
        __builtin_amdgcn_s_setprio(0);                                           \
        BAR(); SCHED();                                                          \
    }while(0)

    // prologue: tile0 {A0,B0,B1,A1}->buf0, tile1 {A0,B0,B1}->buf1
    STG_A0(0,0); STG_B0(0,0); STG_B1(0,0); STG_A1(0,0);
    STG_A0(1,64); STG_B0(1,64); STG_B1(1,64);
    VM6();                       // tile0 landed; {A0,B0,B1}(t1) in flight
    BAR(); SCHED();

    for(int g=0; g<NT; g+=2){
        const bool p2 = (g+2 < NT), p3 = (g+3 < NT);
        TILE(0, 64, 128, true, p2);
        TILE(1, 128, 192, p2, p3);
        pA0[0]+=128; pA0[1]+=128; pA1[0]+=128; pA1[1]+=128;
        pB0[0]+=128; pB0[1]+=128; pB1[0]+=128; pB1[1]+=128;
    }
#undef TILE
#undef STG_A0
#undef STG_A1
#undef STG_B0
#undef STG_B1
#undef MFMA16
#undef READ_BF
#undef READ_AF

    // ---------------- epilogue ----------------
    if (MODE == 0){
        // plain: C[row*N+col]
        #pragma unroll
        for(int mf=0;mf<8;mf++)
            #pragma unroll
            for(int nf=0;nf<4;nf++)
                #pragma unroll
                for(int r=0;r<4;r++){
                    size_t row = rowbase + wm*128 + mf*16 + quad*4 + r;
                    size_t col = colbase + wn*64  + nf*16 + l16;
                    store_c(C + row*(size_t)N + col, acc[mf][nf][r]);
                }
    } else if (colbase < 4096){
        // q/k region: RoPE fused, store to qk (stride QKN)
        const bool ropeW = ((wn&1) == 0);         // wave-uniform
        const float inv = powf(10000.f, -(float)(l16&7)/8.f);
        const bool hi = (l16 >= 8);
        #pragma unroll
        for(int mf=0;mf<8;mf++)
            #pragma unroll
            for(int nf=0;nf<4;nf++)
                #pragma unroll
                for(int r=0;r<4;r++){
                    size_t row = rowbase + wm*128 + mf*16 + quad*4 + r;
                    size_t col = colbase + wn*64  + nf*16 + l16;
                    float val = acc[mf][nf][r];
                    if (nf == 0 && ropeW){        // rope lanes: hd=l16<16
                        int t = (int)(row & 511);
                        float fr = (float)t * inv;
                        float cc = cosf(fr), ss = sinf(fr);
                        float p  = __shfl_xor(val, 8, 64);
                        val = hi ? (val*cc + p*ss) : (val*cc - p*ss);
                    }
                    *( (bf16*)C + row*(size_t)QKN + col ) = __float2bfloat16(val);
                }
    } else {
        // V region: transposed store to vt[bh][d][t], 8B packed over r
        #pragma unroll
        for(int nf=0;nf<4;nf++){
            int col = (int)colbase + wn*64 + nf*16 + l16;
            int h   = (col - 4096) >> 7;
            int d   = col & 127;
            #pragma unroll
            for(int mf=0;mf<8;mf++){
                int row0 = (int)rowbase + wm*128 + mf*16 + quad*4;
                int b = row0 >> 9, t0 = row0 & 511;
                union { s16x4 v; bf16 hh[4]; } o;
                #pragma unroll
                for(int r=0;r<4;r++) o.hh[r] = __float2bfloat16(acc[mf][nf][r]);
                *(s16x4*)(vt + ((size_t)((b<<4)+h)*128 + d)*512 + t0) = o.v;
            }
        }
    }
}

// ---------------- flash attention, S^T dataflow -----------------------------
// (structure unchanged; Q/K now read from qk buffer with stride QKN=4096)
__global__ __launch_bounds__(256, 4) void k_attn(const bf16* __restrict__ qk,
                                                 const bf16* __restrict__ vt,
                                                 bf16* __restrict__ y){
    __shared__ __align__(16) bf16 Ks[64*128];   // [key][d], 16 chunks/row, XOR swizzle
    __shared__ __align__(16) bf16 Vs[128*64];   // [d][key],  8 chunks/row, XOR swizzle
    __shared__ __align__(16) bf16 Ps[64*64];    // [q][key],  8 chunks/row, XOR swizzle
    const int id = blockIdx.x;
    const int x  = id & 7, g = id >> 3;
    const int qt = 7 - (g >> 5);
    const int bh = ((g & 31) << 3) | x;
    const int b = bh >> 4, h = bh & 15;
    const int tid = threadIdx.x, wave = tid>>6, lane = tid&63, quad = lane>>4, l16 = lane&15;
    const int qbase = qt*64;
    const size_t rs = QKN;
    const bf16* Qg = qk + ((size_t)b*SEQT)*rs + (size_t)h*HEADD;
    const bf16* Kg = Qg + DIM_C;
    const bf16* Vtbh = vt + ((size_t)bh*HEADD)*SEQT;

    s16x8 qf[4];
    const int qrow = qbase + wave*16 + l16;     // this lane's q row
    {
        #pragma unroll
        for(int kc=0;kc<4;kc++)
            qf[kc] = *(const s16x8*)(Qg + (size_t)qrow*rs + kc*32 + quad*8);
    }
    f32x4 acc_o[8];                              // O^T: d=dt*16+quad*4+r, q=l16
    #pragma unroll
    for(int dt=0;dt<8;dt++) acc_o[dt] = (f32x4)(0.f);
    float lsum = 0.f;
    const float C2 = 0.12751745f;   // (1/sqrt(128)) * log2(e)
    const int nkt = qt + 1;

    for(int kt=0; kt<nkt; kt++){
        const int kbase = kt*64;
        const bool diag = (kt == nkt-1);
        __syncthreads();                        // Ks/Vs reuse guard
        #pragma unroll
        for(int i=0;i<4;i++){
            int base = wave*256 + i*64;
            int cc   = base + lane;
            int rk   = cc>>4, gk = (cc&15) ^ (rk&7);
            gl16(Kg + (size_t)(kbase+rk)*rs + gk*8, &Ks[base*8]);
            int rv   = cc>>3, gv = (cc&7) ^ (rv&7);
            gl16(Vtbh + (size_t)rv*SEQT + kbase + gv*8, &Vs[base*8]);
        }
        __syncthreads();
        f32x4 sacc[4];
        #pragma unroll
        for(int ni=0;ni<4;ni++) sacc[ni] = (f32x4)(0.f);
        #pragma unroll
        for(int kc=0;kc<4;kc++){
            const int ch = kc*4 + quad;
            #pragma unroll
            for(int ni=0;ni<4;ni++){
                int r = ni*16 + l16;
                s16x8 kf = *(const s16x8*)(&Ks[r*128 + ((ch ^ (r&7))*8)]);
                sacc[ni] = __builtin_amdgcn_mfma_f32_16x16x32_bf16(kf, qf[kc], sacc[ni], 0,0,0);
            }
        }
        {
            const int row = wave*16 + l16;
            const int r7  = row & 7;
            #pragma unroll
            for(int ni=0;ni<4;ni++){
                union { s16x4 v; bf16 hh[4]; } pk;
                #pragma unroll
                for(int rr=0;rr<4;rr++){
                    float e = exp2f(sacc[ni][rr]*C2);
                    if (diag){ int kcol = kbase + ni*16 + quad*4 + rr; if (kcol > qrow) e = 0.f; }
                    lsum += e;
                    pk.hh[rr] = __float2bfloat16(e);
                }
                int c = ni*2 + (quad>>1);            // 8-elt chunk index
                *(s16x4*)(&Ps[row*64 + ((c ^ r7)<<3) + ((quad&1)<<2)]) = pk.v;
            }
        }
        #pragma unroll
        for(int kk=0;kk<2;kk++){
            int rw = wave*16 + l16;
            int c  = kk*4 + quad;
            s16x8 pf = *(const s16x8*)(&Ps[rw*64 + ((c ^ (rw&7))<<3)]);
            #pragma unroll
            for(int dt=0;dt<8;dt++){
                int r = dt*16 + l16;
                s16x8 vf = *(const s16x8*)(&Vs[r*64 + ((c ^ (r&7))<<3)]);
                acc_o[dt] = __builtin_amdgcn_mfma_f32_16x16x32_bf16(vf, pf, acc_o[dt], 0,0,0);
            }
        }
    }
    lsum += __shfl_xor(lsum, 16, 64);
    lsum += __shfl_xor(lsum, 32, 64);
    float inv_l = 1.f/lsum;
    size_t base = ((size_t)(b*SEQT) + qrow)*DIM_C + (size_t)h*HEADD;
    #pragma unroll
    for(int dt=0;dt<8;dt++){
        union { s16x4 v; bf16 hh[4]; } o;
        #pragma unroll
        for(int rr=0;rr<4;rr++) o.hh[rr] = __float2bfloat16(acc_o[dt][rr]*inv_l);
        *(s16x4*)(y + base + dt*16 + quad*4) = o.v;
    }
}

extern "C" void kernel_launch(void* const* d_in, const int* in_sizes, int n_in,
                              void* d_out, int out_size, void* d_ws, size_t ws_size,
                              hipStream_t stream){
    const float* x    = (const float*)d_in[0];
    const float* Wqkv = (const float*)d_in[1];
    const float* Wout = (const float*)d_in[2];
    float* out = (float*)d_out;
    char* ws = (char*)d_ws;
    // ws layout (bytes), total 192 MB, no live aliasing:
    bf16* xb    = (bf16*)(ws + 0);            //  32 MB: 8192x2048 (A of GEMM1)
    bf16* wqkvT = (bf16*)(ws + 33554432);     //  24 MB: 6144x2048
    bf16* woutT = (bf16*)(ws + 58720256);     //   8 MB: 2048x2048
    bf16* qkb   = (bf16*)(ws + 67108864);     //  64 MB: 8192x4096 (q,k roped)
    bf16* vt    = (bf16*)(ws + 134217728);    //  32 MB: [b][h][128][512]
    bf16* yb    = (bf16*)(ws + 167772160);    //  32 MB: 8192x2048

    k_cvt<<<dim3(MROWS*DIM_C/8/256), 256, 0, stream>>>(x, xb, MROWS*DIM_C);
    dim3 tb(32,8);
    k_transpose_cvt<<<dim3(QKVN/32, DIM_C/32), tb, 0, stream>>>(Wqkv, wqkvT, DIM_C, QKVN);
    k_transpose_cvt<<<dim3(DIM_C/32, DIM_C/32), tb, 0, stream>>>(Wout, woutT, DIM_C, DIM_C);

    // GEMM1: qkv projection, rope fused (q,k -> qkb), V transposed -> vt
    k_gemm256<bf16,1><<<dim3(QKVN/256, MROWS/256), 512, 0, stream>>>(
        xb, wqkvT, qkb, vt, MROWS, QKVN, DIM_C);
    k_attn<<<dim3(SEQT/64 * NHEADS * NBATCH), 256, 0, stream>>>(qkb, vt, yb);
    k_gemm256<float,0><<<dim3(DIM_C/256, MROWS/256), 512, 0, stream>>>(
        yb, woutT, out, (bf16*)nullptr, MROWS, DIM_C, DIM_C);
}

// Round 12
// 498.977 us; speedup vs baseline: 1.0214x; 1.0214x over previous
//
#include <hip/hip_runtime.h>
#include <hip/hip_bf16.h>
#include <math.h>

using bf16 = __hip_bfloat16;
typedef short s16x8 __attribute__((ext_vector_type(8)));
typedef short s16x4 __attribute__((ext_vector_type(4)));
typedef float f32x4 __attribute__((ext_vector_type(4)));

#define DIM_C   2048
#define NHEADS  16
#define HEADD   128
#define SEQT    512
#define NBATCH  16
#define MROWS   (NBATCH*SEQT)   // 8192
#define QKVN    (3*DIM_C)       // 6144
#define QKN     (2*DIM_C)       // 4096 (q,k only; v goes to vbuf then vt)

static __device__ __forceinline__ float bf2f(bf16 v){ return __bfloat162float(v); }

// async global->LDS, 16B per lane; LDS dest = wave-uniform base + lane*16
static __device__ __forceinline__ void gl16(const void* g, void* l){
    __builtin_amdgcn_global_load_lds(
        reinterpret_cast<__attribute__((address_space(1))) void*>(
            (unsigned long long)g),
        reinterpret_cast<__attribute__((address_space(3))) void*>(
            (unsigned long long)l),
        16, 0, 0);
}

// ---------------- convert fp32 -> bf16, 8 elts/thread ----------------
__global__ void k_cvt(const float* __restrict__ in, bf16* __restrict__ out, int n){
    size_t i = ((size_t)blockIdx.x*blockDim.x + threadIdx.x)*8;
    if (i >= (size_t)n) return;
    float4 a = *(const float4*)(in+i);
    float4 b = *(const float4*)(in+i+4);
    union { bf16 o[8]; s16x8 v; } u;
    u.o[0]=__float2bfloat16(a.x); u.o[1]=__float2bfloat16(a.y);
    u.o[2]=__float2bfloat16(a.z); u.o[3]=__float2bfloat16(a.w);
    u.o[4]=__float2bfloat16(b.x); u.o[5]=__float2bfloat16(b.y);
    u.o[6]=__float2bfloat16(b.z); u.o[7]=__float2bfloat16(b.w);
    *(s16x8*)(out+i) = u.v;
}

// ---------------- transpose + convert: in fp32 [R][C] -> out bf16 [C][R] ----
__global__ void k_transpose_cvt(const float* __restrict__ in, bf16* __restrict__ out,
                                int R, int C){
    __shared__ float tile[32][33];
    int c0 = blockIdx.x*32, r0 = blockIdx.y*32;
    int tx = threadIdx.x, ty = threadIdx.y;           // block (32,8)
    #pragma unroll
    for(int i=0;i<4;i++)
        tile[ty+8*i][tx] = in[(size_t)(r0+ty+8*i)*C + c0+tx];
    __syncthreads();
    #pragma unroll
    for(int i=0;i<4;i++)
        out[(size_t)(c0+ty+8*i)*R + r0+tx] = __float2bfloat16(tile[tx][ty+8*i]);
}

// ---------------- V^T: vbuf [b][t][2048] -> vt [b][h][d][t] ----------------
__global__ void k_vtrans(const bf16* __restrict__ vbuf, bf16* __restrict__ vt){
    __shared__ bf16 tile[32][33];
    int t0 = blockIdx.x*32, d0 = blockIdx.y*32, bh = blockIdx.z;
    int b = bh>>4, h = bh&15;
    int tx = threadIdx.x, ty = threadIdx.y;           // block (32,8)
    const bf16* src = vbuf + ((size_t)b*SEQT)*DIM_C + (size_t)h*HEADD;
    #pragma unroll
    for(int i=0;i<4;i++)
        tile[ty+8*i][tx] = src[(size_t)(t0+ty+8*i)*DIM_C + d0+tx];
    __syncthreads();
    bf16* dst = vt + ((size_t)bh*HEADD)*SEQT;
    #pragma unroll
    for(int i=0;i<4;i++)
        dst[(size_t)(d0+ty+8*i)*SEQT + t0+tx] = tile[tx][ty+8*i];
}

// ---------------- bf16 GEMM 256x256 tile, 4-phase, strength-reduced --------
// Core K-loop = R7-v4 EXACTLY.  MODE 0: plain C store (GEMM2).
// MODE 1 (GEMM1): colbase<4096 -> q/k with fused RoPE -> qk (stride QKN);
//                 colbase>=4096 -> V contiguous -> vbuf[b][t][2048]
//                 (R10's vt-scatter REVERTED: +71MB fetch, +32us epilogue).
static __device__ __forceinline__ void store_c(bf16* p, float v){ *p = __float2bfloat16(v); }
static __device__ __forceinline__ void store_c(float* p, float v){ *p = v; }

#define BAR()   __builtin_amdgcn_s_barrier()
#define SCHED() __builtin_amdgcn_sched_barrier(0)
#define LGKM0() asm volatile("s_waitcnt lgkmcnt(0)" ::: "memory")
#define VM6()   asm volatile("s_waitcnt vmcnt(6)"   ::: "memory")
#define VM4()   asm volatile("s_waitcnt vmcnt(4)"   ::: "memory")
#define VM0()   asm volatile("s_waitcnt vmcnt(0)"   ::: "memory")

template<typename OutT, int MODE>
__global__ __launch_bounds__(512, 2) void k_gemm256(const bf16* __restrict__ A,
                                                    const bf16* __restrict__ Bt,
                                                    OutT* __restrict__ C,
                                                    bf16* __restrict__ vbuf,
                                                    int M, int N, int K){
    __shared__ __align__(16) bf16 AS[2][2][128*64];
    __shared__ __align__(16) bf16 BS[2][2][128*64];
    const int tid = threadIdx.x;
    const int wave = tid>>6, lane = tid&63, quad = lane>>4, l16 = lane&15;
    const int wm = wave>>2, wn = wave&3;

    // bijective XCD swizzle (grid % 8 == 0 for both GEMMs here)
    const int nbx = gridDim.x;
    const int nwg = gridDim.x*gridDim.y;
    int bid = blockIdx.y*nbx + blockIdx.x;
    int swz = (bid&7)*(nwg>>3) + (bid>>3);
    int by = swz / nbx, bx = swz - by*nbx;
    const size_t rowbase = (size_t)by * 256;
    const size_t colbase = (size_t)bx * 256;
    const int NT = K>>6;

    f32x4 acc[8][4];
    #pragma unroll
    for(int i=0;i<8;i++)
        #pragma unroll
        for(int j=0;j<4;j++) acc[i][j] = (f32x4)(0.f);

    // ---- stage decode (once): per i in {0,1} a chunk id, inverse swizzle ----
    int cb0 = wave*64,        cc0 = cb0 + lane;
    int cb1 = 512 + wave*64,  cc1 = cb1 + lane;
    int ri0 = cc0>>3, gg0 = (cc0&7)^(ri0&7);
    int ri1 = cc1>>3, gg1 = (cc1&7)^(ri1&7);
    // rolling global pointers (element units); advanced +=128 per tile-pair
    const bf16* pA0[2];  const bf16* pA1[2];
    const bf16* pB0[2];  const bf16* pB1[2];
    pA0[0] = A  + (rowbase + (size_t)(((ri0>>6)<<7) + (ri0&63)))*(size_t)K + gg0*8;
    pA0[1] = A  + (rowbase + (size_t)(((ri1>>6)<<7) + (ri1&63)))*(size_t)K + gg1*8;
    pA1[0] = pA0[0] + (size_t)64*K;  pA1[1] = pA0[1] + (size_t)64*K;
    pB0[0] = Bt + (colbase + (size_t)(((ri0>>5)<<6) + (ri0&31)))*(size_t)K + gg0*8;
    pB0[1] = Bt + (colbase + (size_t)(((ri1>>5)<<6) + (ri1&31)))*(size_t)K + gg1*8;
    pB1[0] = pB0[0] + (size_t)32*K;  pB1[1] = pB0[1] + (size_t)32*K;
    const int dE0 = cb0*8, dE1 = cb1*8;      // LDS dest element offsets (plane-local)

    // ---- ds_read base offsets (thread-invariant, element units) ----
    const int x7 = l16 & 7;
    int aB[2], bB[2];
    #pragma unroll
    for(int kc=0;kc<2;kc++){
        int ch = ((kc*4+quad) ^ x7) << 3;
        aB[kc] = (wm*64 + l16)*64 + ch;
        bB[kc] = (wn*32 + l16)*64 + ch;
    }

    s16x8 af[4][2], bf0[2][2], bf1[2][2];

#define READ_AF(BUF,MH) do{ _Pragma("unroll")                                    \
    for(int kc_=0;kc_<2;kc_++){ _Pragma("unroll")                                \
        for(int mi_=0;mi_<4;mi_++)                                               \
            af[mi_][kc_] = *(const s16x8*)(&AS[BUF][MH][aB[kc_] + mi_*1024]); } }while(0)
#define READ_BF(BUF,NH,DST) do{ _Pragma("unroll")                                \
    for(int kc_=0;kc_<2;kc_++){ _Pragma("unroll")                                \
        for(int nj_=0;nj_<2;nj_++)                                               \
            DST[nj_][kc_] = *(const s16x8*)(&BS[BUF][NH][bB[kc_] + nj_*1024]); } }while(0)
// kc-outer: dependent same-acc MFMAs 8 apart
#define MFMA16(BFR,MH,NH) do{ _Pragma("unroll")                                  \
    for(int kc_=0;kc_<2;kc_++){ _Pragma("unroll")                                \
        for(int mi_=0;mi_<4;mi_++){ _Pragma("unroll")                            \
            for(int nj_=0;nj_<2;nj_++)                                           \
                acc[(MH)*4+mi_][(NH)*2+nj_] =                                    \
                    __builtin_amdgcn_mfma_f32_16x16x32_bf16(                     \
                        af[mi_][kc_], BFR[nj_][kc_],                             \
                        acc[(MH)*4+mi_][(NH)*2+nj_], 0,0,0); } } }while(0)

#define STG_A0(BUF,OFF) do{ gl16(pA0[0]+(OFF), &AS[BUF][0][dE0]);                \
                            gl16(pA0[1]+(OFF), &AS[BUF][0][dE1]); }while(0)
#define STG_A1(BUF,OFF) do{ gl16(pA1[0]+(OFF), &AS[BUF][1][dE0]);                \
                            gl16(pA1[1]+(OFF), &AS[BUF][1][dE1]); }while(0)
#define STG_B0(BUF,OFF) do{ gl16(pB0[0]+(OFF), &BS[BUF][0][dE0]);                \
                            gl16(pB0[1]+(OFF), &BS[BUF][0][dE1]); }while(0)
#define STG_B1(BUF,OFF) do{ gl16(pB1[0]+(OFF), &BS[BUF][1][dE0]);                \
                            gl16(pB1[1]+(OFF), &BS[BUF][1][dE1]); }while(0)

#define TILE(BUF,O1,O2,GA1,GR)                                                   \
    do{                                                                          \
        /* P1 */                                                                 \
        if (GA1) STG_A1(BUF^1, O1);                                              \
        READ_AF(BUF,0); READ_BF(BUF,0,bf0);                                      \
        BAR(); LGKM0(); SCHED();                                                 \
        __builtin_amdgcn_s_setprio(1);  MFMA16(bf0,0,0);                         \
        __builtin_amdgcn_s_setprio(0);                                           \
        BAR(); SCHED();                                                          \
        /* P2 */                                                                 \
        if (GR) STG_A0(BUF,O2);                                                  \
        READ_BF(BUF,1,bf1);                                                      \
        BAR(); LGKM0(); SCHED();                                                 \
        __builtin_amdgcn_s_setprio(1);  MFMA16(bf1,0,1);                         \
        __builtin_amdgcn_s_setprio(0);                                           \
        BAR(); SCHED();                                                          \
        /* P3 */                                                                 \
        if (GR) STG_B0(BUF,O2);                                                  \
        READ_AF(BUF,1);                                                          \
        BAR(); LGKM0(); SCHED();                                                 \
        __builtin_amdgcn_s_setprio(1);  MFMA16(bf0,1,0);                         \
        __builtin_amdgcn_s_setprio(0);                                           \
        BAR(); SCHED();                                                          \
        /* P4 */                                                                 \
        if (GR){ STG_B1(BUF,O2); VM6(); } else { VM0(); }                        \
        BAR(); SCHED();                                                          \
        __builtin_amdgcn_s_setprio(1);  MFMA16(bf1,1,1);                         \
        __builtin_amdgcn_s_setprio(0);                                           \
        BAR(); SCHED();                                                          \
    }while(0)

    // prologue: tile0 {A0,B0,B1,A1}->buf0, tile1 {A0,B0,B1}->buf1
    STG_A0(0,0); STG_B0(0,0); STG_B1(0,0); STG_A1(0,0);
    STG_A0(1,64); STG_B0(1,64); STG_B1(1,64);
    VM6();                       // tile0 landed; {A0,B0,B1}(t1) in flight
    BAR(); SCHED();

    for(int g=0; g<NT; g+=2){
        const bool p2 = (g+2 < NT), p3 = (g+3 < NT);
        TILE(0, 64, 128, true, p2);
        TILE(1, 128, 192, p2, p3);
        pA0[0]+=128; pA0[1]+=128; pA1[0]+=128; pA1[1]+=128;
        pB0[0]+=128; pB0[1]+=128; pB1[0]+=128; pB1[1]+=128;
    }
#undef TILE
#undef STG_A0
#undef STG_A1
#undef STG_B0
#undef STG_B1
#undef MFMA16
#undef READ_BF
#undef READ_AF

    // ---------------- epilogue ----------------
    if (MODE == 0){
        // plain: C[row*N+col]
        #pragma unroll
        for(int mf=0;mf<8;mf++)
            #pragma unroll
            for(int nf=0;nf<4;nf++)
                #pragma unroll
                for(int r=0;r<4;r++){
                    size_t row = rowbase + wm*128 + mf*16 + quad*4 + r;
                    size_t col = colbase + wn*64  + nf*16 + l16;
                    store_c(C + row*(size_t)N + col, acc[mf][nf][r]);
                }
    } else if (colbase < 4096){
        // q/k region: RoPE fused, store to qk (stride QKN)
        const bool ropeW = ((wn&1) == 0);         // wave-uniform
        const float inv = powf(10000.f, -(float)(l16&7)/8.f);
        const bool hi = (l16 >= 8);
        #pragma unroll
        for(int mf=0;mf<8;mf++)
            #pragma unroll
            for(int nf=0;nf<4;nf++)
                #pragma unroll
                for(int r=0;r<4;r++){
                    size_t row = rowbase + wm*128 + mf*16 + quad*4 + r;
                    size_t col = colbase + wn*64  + nf*16 + l16;
                    float val = acc[mf][nf][r];
                    if (nf == 0 && ropeW){        // rope lanes: hd=l16<16
                        int t = (int)(row & 511);
                        float fr = (float)t * inv;
                        float cc = cosf(fr), ss = sinf(fr);
                        float p  = __shfl_xor(val, 8, 64);
                        val = hi ? (val*cc + p*ss) : (val*cc - p*ss);
                    }
                    *( (bf16*)C + row*(size_t)QKN + col ) = __float2bfloat16(val);
                }
    } else {
        // V region: contiguous store to vbuf[b][t][2048]
        #pragma unroll
        for(int mf=0;mf<8;mf++)
            #pragma unroll
            for(int nf=0;nf<4;nf++)
                #pragma unroll
                for(int r=0;r<4;r++){
                    size_t row = rowbase + wm*128 + mf*16 + quad*4 + r;
                    size_t col = colbase + wn*64  + nf*16 + l16 - 4096;
                    vbuf[row*(size_t)DIM_C + col] = __float2bfloat16(acc[mf][nf][r]);
                }
    }
}

// ---------------- flash attention, S^T dataflow, pipelined staging ---------
// v2: counted-vmcnt K/V pipeline (GEMM T3/T4 ledger ported).  All VMEM in
// the loop is gl16 (4 K-chunks + 4 V-chunks per thread per tile); qf's 4
// global loads are oldest-in-FIFO and drain at the first VM4.
// Per tile kt: VM4+BAR (K(kt) landed; V(kt) in flight) -> QK^T -> BAR ->
// issue K(kt+1) -> softmax (hides issue) -> VM4 (drains V(kt), leaves
// K(kt+1)) / VM0 at tail -> BAR -> PV -> BAR -> issue V(kt+1).
// WAR: stageK after BAR(post-QK^T), stageV after BAR(post-PV). LDS still
// 40KB -> 4 blocks/CU.
__global__ __launch_bounds__(256, 4) void k_attn(const bf16* __restrict__ qk,
                                                 const bf16* __restrict__ vt,
                                                 bf16* __restrict__ y){
    __shared__ __align__(16) bf16 Ks[64*128];   // [key][d], 16 chunks/row, XOR swizzle
    __shared__ __align__(16) bf16 Vs[128*64];   // [d][key],  8 chunks/row, XOR swizzle
    __shared__ __align__(16) bf16 Ps[64*64];    // [q][key],  8 chunks/row, XOR swizzle
    const int id = blockIdx.x;
    const int x  = id & 7, g = id >> 3;
    const int qt = 7 - (g >> 5);
    const int bh = ((g & 31) << 3) | x;
    const int b = bh >> 4, h = bh & 15;
    const int tid = threadIdx.x, wave = tid>>6, lane = tid&63, quad = lane>>4, l16 = lane&15;
    const int qbase = qt*64;
    const size_t rs = QKN;
    const bf16* Qg = qk + ((size_t)b*SEQT)*rs + (size_t)h*HEADD;
    const bf16* Kg = Qg + DIM_C;
    const bf16* Vtbh = vt + ((size_t)bh*HEADD)*SEQT;

    s16x8 qf[4];
    const int qrow = qbase + wave*16 + l16;     // this lane's q row
    {
        #pragma unroll
        for(int kc=0;kc<4;kc++)
            qf[kc] = *(const s16x8*)(Qg + (size_t)qrow*rs + kc*32 + quad*8);
    }
    f32x4 acc_o[8];                              // O^T: d=dt*16+quad*4+r, q=l16
    #pragma unroll
    for(int dt=0;dt<8;dt++) acc_o[dt] = (f32x4)(0.f);
    float lsum = 0.f;
    const float C2 = 0.12751745f;   // (1/sqrt(128)) * log2(e)
    const int nkt = qt + 1;

    auto stageK = [&](int kb){
        #pragma unroll
        for(int i=0;i<4;i++){
            int base = wave*256 + i*64;
            int cc   = base + lane;
            int rk   = cc>>4, gk = (cc&15) ^ (rk&7);
            gl16(Kg + (size_t)(kb+rk)*rs + gk*8, &Ks[base*8]);
        }
    };
    auto stageV = [&](int kb){
        #pragma unroll
        for(int i=0;i<4;i++){
            int base = wave*256 + i*64;
            int cc   = base + lane;
            int rv   = cc>>3, gv = (cc&7) ^ (rv&7);
            gl16(Vtbh + (size_t)rv*SEQT + kb + gv*8, &Vs[base*8]);
        }
    };

    stageK(0); stageV(0);                       // prologue

    for(int kt=0; kt<nkt; kt++){
        const int kbase = kt*64;
        const bool diag = (kt == nkt-1);
        const bool more = (kt+1 < nkt);
        VM4(); BAR(); SCHED();                  // K(kt) landed everywhere
        // S^T = K Q^T: A = K rows (m=key), B = Q rows (n=q)
        f32x4 sacc[4];
        #pragma unroll
        for(int ni=0;ni<4;ni++) sacc[ni] = (f32x4)(0.f);
        __builtin_amdgcn_s_setprio(1);
        #pragma unroll
        for(int kc=0;kc<4;kc++){
            const int ch = kc*4 + quad;
            #pragma unroll
            for(int ni=0;ni<4;ni++){
                int r = ni*16 + l16;
                s16x8 kf = *(const s16x8*)(&Ks[r*128 + ((ch ^ (r&7))*8)]);
                sacc[ni] = __builtin_amdgcn_mfma_f32_16x16x32_bf16(kf, qf[kc], sacc[ni], 0,0,0);
            }
        }
        __builtin_amdgcn_s_setprio(0);
        SCHED(); BAR(); SCHED();                // Ks reads done (all waves)
        if (more) stageK(kbase+64);             // K(kt+1) issue, hidden by softmax
        // P^T = exp2(S^T*C2), causal mask -> 0; write wave-private Ps rows.
        {
            const int row = wave*16 + l16;
            const int r7  = row & 7;
            #pragma unroll
            for(int ni=0;ni<4;ni++){
                union { s16x4 v; bf16 hh[4]; } pk;
                #pragma unroll
                for(int rr=0;rr<4;rr++){
                    float e = exp2f(sacc[ni][rr]*C2);
                    if (diag){ int kcol = kbase + ni*16 + quad*4 + rr; if (kcol > qrow) e = 0.f; }
                    lsum += e;
                    pk.hh[rr] = __float2bfloat16(e);
                }
                int c = ni*2 + (quad>>1);            // 8-elt chunk index
                *(s16x4*)(&Ps[row*64 + ((c ^ r7)<<3) + ((quad&1)<<2)]) = pk.v;
            }
        }
        if (more){ VM4(); } else { VM0(); }     // V(kt) landed (leaves K(kt+1))
        BAR(); SCHED();
        // O^T += V^T P^T  (A = vf: m=d, k=key; B = pf: n=q, k=key)
        __builtin_amdgcn_s_setprio(1);
        #pragma unroll
        for(int kk=0;kk<2;kk++){
            int rw = wave*16 + l16;
            int c  = kk*4 + quad;
            s16x8 pf = *(const s16x8*)(&Ps[rw*64 + ((c ^ (rw&7))<<3)]);
            #pragma unroll
            for(int dt=0;dt<8;dt++){
                int r = dt*16 + l16;
                s16x8 vf = *(const s16x8*)(&Vs[r*64 + ((c ^ (r&7))<<3)]);
                acc_o[dt] = __builtin_amdgcn_mfma_f32_16x16x32_bf16(vf, pf, acc_o[dt], 0,0,0);
            }
        }
        __builtin_amdgcn_s_setprio(0);
        SCHED(); BAR(); SCHED();                // Vs reads done (all waves)
        if (more) stageV(kbase+64);             // V(kt+1) issue
    }
    lsum += __shfl_xor(lsum, 16, 64);
    lsum += __shfl_xor(lsum, 32, 64);
    float inv_l = 1.f/lsum;
    size_t base = ((size_t)(b*SEQT) + qrow)*DIM_C + (size_t)h*HEADD;
    #pragma unroll
    for(int dt=0;dt<8;dt++){
        union { s16x4 v; bf16 hh[4]; } o;
        #pragma unroll
        for(int rr=0;rr<4;rr++) o.hh[rr] = __float2bfloat16(acc_o[dt][rr]*inv_l);
        *(s16x4*)(y + base + dt*16 + quad*4) = o.v;
    }
}

extern "C" void kernel_launch(void* const* d_in, const int* in_sizes, int n_in,
                              void* d_out, int out_size, void* d_ws, size_t ws_size,
                              hipStream_t stream){
    const float* x    = (const float*)d_in[0];
    const float* Wqkv = (const float*)d_in[1];
    const float* Wout = (const float*)d_in[2];
    float* out = (float*)d_out;
    char* ws = (char*)d_ws;
    // ws layout (bytes), 192 MB total.  yb aliases vbuf (vbuf dead after
    // k_vtrans; yb written by k_attn afterwards).
    bf16* xb    = (bf16*)(ws + 0);            //  32 MB: 8192x2048 (A of GEMM1)
    bf16* wqkvT = (bf16*)(ws + 33554432);     //  24 MB: 6144x2048
    bf16* woutT = (bf16*)(ws + 58720256);     //   8 MB: 2048x2048
    bf16* qkb   = (bf16*)(ws + 67108864);     //  64 MB: 8192x4096 (q,k roped)
    bf16* vbuf  = (bf16*)(ws + 134217728);    //  32 MB: [b][t][2048]
    bf16* vt    = (bf16*)(ws + 167772160);    //  32 MB: [b][h][128][512]
    bf16* yb    = (bf16*)(ws + 134217728);    //  32 MB: aliases vbuf

    k_cvt<<<dim3(MROWS*DIM_C/8/256), 256, 0, stream>>>(x, xb, MROWS*DIM_C);
    dim3 tb(32,8);
    k_transpose_cvt<<<dim3(QKVN/32, DIM_C/32), tb, 0, stream>>>(Wqkv, wqkvT, DIM_C, QKVN);
    k_transpose_cvt<<<dim3(DIM_C/32, DIM_C/32), tb, 0, stream>>>(Wout, woutT, DIM_C, DIM_C);

    // GEMM1: qkv projection, rope fused (q,k -> qkb), V -> vbuf (contiguous)
    k_gemm256<bf16,1><<<dim3(QKVN/256, MROWS/256), 512, 0, stream>>>(
        xb, wqkvT, qkb, vbuf, MROWS, QKVN, DIM_C);
    k_vtrans<<<dim3(SEQT/32, HEADD/32, NBATCH*NHEADS), tb, 0, stream>>>(vbuf, vt);
    k_attn<<<dim3(SEQT/64 * NHEADS * NBATCH), 256, 0, stream>>>(qkb, vt, yb);
    k_gemm256<float,0><<<dim3(DIM_C/256, MROWS/256), 512, 0, stream>>>(
        yb, woutT, out, (bf16*)nullptr, MROWS, DIM_C, DIM_C);
}

// Round 13
// 481.619 us; speedup vs baseline: 1.0582x; 1.0360x over previous
//
#include <hip/hip_runtime.h>
#include <hip/hip_bf16.h>
#include <math.h>

using bf16 = __hip_bfloat16;
typedef short s16x8 __attribute__((ext_vector_type(8)));
typedef short s16x4 __attribute__((ext_vector_type(4)));
typedef float f32x4 __attribute__((ext_vector_type(4)));

#define DIM_C   2048
#define NHEADS  16
#define HEADD   128
#define SEQT    512
#define NBATCH  16
#define MROWS   (NBATCH*SEQT)   // 8192
#define QKVN    (3*DIM_C)       // 6144

static __device__ __forceinline__ float bf2f(bf16 v){ return __bfloat162float(v); }

// async global->LDS, 16B per lane; LDS dest = wave-uniform base + lane*16
static __device__ __forceinline__ void gl16(const void* g, void* l){
    __builtin_amdgcn_global_load_lds(
        reinterpret_cast<__attribute__((address_space(1))) void*>(
            (unsigned long long)g),
        reinterpret_cast<__attribute__((address_space(3))) void*>(
            (unsigned long long)l),
        16, 0, 0);
}

// ---------------- convert fp32 -> bf16, 8 elts/thread ----------------
__global__ void k_cvt(const float* __restrict__ in, bf16* __restrict__ out, int n){
    size_t i = ((size_t)blockIdx.x*blockDim.x + threadIdx.x)*8;
    if (i >= (size_t)n) return;
    float4 a = *(const float4*)(in+i);
    float4 b = *(const float4*)(in+i+4);
    union { bf16 o[8]; s16x8 v; } u;
    u.o[0]=__float2bfloat16(a.x); u.o[1]=__float2bfloat16(a.y);
    u.o[2]=__float2bfloat16(a.z); u.o[3]=__float2bfloat16(a.w);
    u.o[4]=__float2bfloat16(b.x); u.o[5]=__float2bfloat16(b.y);
    u.o[6]=__float2bfloat16(b.z); u.o[7]=__float2bfloat16(b.w);
    *(s16x8*)(out+i) = u.v;
}

// ---------------- transpose + convert: in fp32 [R][C] -> out bf16 [C][R] ----
__global__ void k_transpose_cvt(const float* __restrict__ in, bf16* __restrict__ out,
                                int R, int C){
    __shared__ float tile[32][33];
    int c0 = blockIdx.x*32, r0 = blockIdx.y*32;
    int tx = threadIdx.x, ty = threadIdx.y;           // block (32,8)
    #pragma unroll
    for(int i=0;i<4;i++)
        tile[ty+8*i][tx] = in[(size_t)(r0+ty+8*i)*C + c0+tx];
    __syncthreads();
    #pragma unroll
    for(int i=0;i<4;i++)
        out[(size_t)(c0+ty+8*i)*R + r0+tx] = __float2bfloat16(tile[tx][ty+8*i]);
}

// ---------------- V^T: qkv V-section [b][t][h][d] -> vt [b][h][d][t] -------
__global__ void k_vtrans(const bf16* __restrict__ qkv, bf16* __restrict__ vt){
    __shared__ bf16 tile[32][33];
    int t0 = blockIdx.x*32, d0 = blockIdx.y*32, bh = blockIdx.z;
    int b = bh>>4, h = bh&15;
    int tx = threadIdx.x, ty = threadIdx.y;           // block (32,8)
    const bf16* src = qkv + ((size_t)b*SEQT)*QKVN + 2*DIM_C + (size_t)h*HEADD;
    #pragma unroll
    for(int i=0;i<4;i++)
        tile[ty+8*i][tx] = src[(size_t)(t0+ty+8*i)*QKVN + d0+tx];
    __syncthreads();
    bf16* dst = vt + ((size_t)bh*HEADD)*SEQT;
    #pragma unroll
    for(int i=0;i<4;i++)
        dst[(size_t)(d0+ty+8*i)*SEQT + t0+tx] = tile[tx][ty+8*i];
}

// ---------------- in-place RoPE on q,k (first 16 dims of each head) --------
__global__ void k_rope(bf16* __restrict__ qkv){
    int tid = blockIdx.x*blockDim.x + threadIdx.x;    // 2^21 threads
    int i   = tid & 7;        int rest = tid >> 3;
    int qk  = rest & 1;       rest >>= 1;
    int h   = rest & 15;      rest >>= 4;
    int t   = rest & 511;     int b = rest >> 9;
    size_t base = ((size_t)(b*SEQT + t))*QKVN + (size_t)qk*DIM_C + (size_t)h*HEADD;
    float x1 = bf2f(qkv[base+i]), x2 = bf2f(qkv[base+i+8]);
    float inv = powf(10000.f, -(float)i/8.f);
    float fr = (float)t * inv;
    float c = cosf(fr), s = sinf(fr);
    qkv[base+i]   = __float2bfloat16(x1*c - x2*s);
    qkv[base+i+8] = __float2bfloat16(x2*c + x1*s);
}

// ---------------- bf16 GEMM 256x256 tile, 4-phase, strength-reduced --------
// R7-v4 EXACTLY (fusion reverted: +33us/+74MB FETCH tracked to the rope
// epilogue, not the V-store pattern — R10 vs R12 both ~392MB).
static __device__ __forceinline__ void store_c(bf16* p, float v){ *p = __float2bfloat16(v); }
static __device__ __forceinline__ void store_c(float* p, float v){ *p = v; }

#define BAR()   __builtin_amdgcn_s_barrier()
#define SCHED() __builtin_amdgcn_sched_barrier(0)
#define LGKM0() asm volatile("s_waitcnt lgkmcnt(0)" ::: "memory")
#define VM6()   asm volatile("s_waitcnt vmcnt(6)"   ::: "memory")
#define VM4()   asm volatile("s_waitcnt vmcnt(4)"   ::: "memory")
#define VM0()   asm volatile("s_waitcnt vmcnt(0)"   ::: "memory")

template<typename OutT>
__global__ __launch_bounds__(512, 2) void k_gemm256(const bf16* __restrict__ A,
                                                    const bf16* __restrict__ Bt,
                                                    OutT* __restrict__ C,
                                                    int M, int N, int K){
    __shared__ __align__(16) bf16 AS[2][2][128*64];
    __shared__ __align__(16) bf16 BS[2][2][128*64];
    const int tid = threadIdx.x;
    const int wave = tid>>6, lane = tid&63, quad = lane>>4, l16 = lane&15;
    const int wm = wave>>2, wn = wave&3;

    // bijective XCD swizzle (grid % 8 == 0 for both GEMMs here)
    const int nbx = gridDim.x;
    const int nwg = gridDim.x*gridDim.y;
    int bid = blockIdx.y*nbx + blockIdx.x;
    int swz = (bid&7)*(nwg>>3) + (bid>>3);
    int by = swz / nbx, bx = swz - by*nbx;
    const size_t rowbase = (size_t)by * 256;
    const size_t colbase = (size_t)bx * 256;
    const int NT = K>>6;

    f32x4 acc[8][4];
    #pragma unroll
    for(int i=0;i<8;i++)
        #pragma unroll
        for(int j=0;j<4;j++) acc[i][j] = (f32x4)(0.f);

    // ---- stage decode (once): per i in {0,1} a chunk id, inverse swizzle ----
    int cb0 = wave*64,        cc0 = cb0 + lane;
    int cb1 = 512 + wave*64,  cc1 = cb1 + lane;
    int ri0 = cc0>>3, gg0 = (cc0&7)^(ri0&7);
    int ri1 = cc1>>3, gg1 = (cc1&7)^(ri1&7);
    // rolling global pointers (element units); advanced +=128 per tile-pair
    const bf16* pA0[2];  const bf16* pA1[2];
    const bf16* pB0[2];  const bf16* pB1[2];
    pA0[0] = A  + (rowbase + (size_t)(((ri0>>6)<<7) + (ri0&63)))*(size_t)K + gg0*8;
    pA0[1] = A  + (rowbase + (size_t)(((ri1>>6)<<7) + (ri1&63)))*(size_t)K + gg1*8;
    pA1[0] = pA0[0] + (size_t)64*K;  pA1[1] = pA0[1] + (size_t)64*K;
    pB0[0] = Bt + (colbase + (size_t)(((ri0>>5)<<6) + (ri0&31)))*(size_t)K + gg0*8;
    pB0[1] = Bt + (colbase + (size_t)(((ri1>>5)<<6) + (ri1&31)))*(size_t)K + gg1*8;
    pB1[0] = pB0[0] + (size_t)32*K;  pB1[1] = pB0[1] + (size_t)32*K;
    const int dE0 = cb0*8, dE1 = cb1*8;      // LDS dest element offsets (plane-local)

    // ---- ds_read base offsets (thread-invariant, element units) ----
    const int x7 = l16 & 7;
    int aB[2], bB[2];
    #pragma unroll
    for(int kc=0;kc<2;kc++){
        int ch = ((kc*4+quad) ^ x7) << 3;
        aB[kc] = (wm*64 + l16)*64 + ch;
        bB[kc] = (wn*32 + l16)*64 + ch;
    }

    s16x8 af[4][2], bf0[2][2], bf1[2][2];

#define READ_AF(BUF,MH) do{ _Pragma("unroll")                                    \
    for(int kc_=0;kc_<2;kc_++){ _Pragma("unroll")                                \
        for(int mi_=0;mi_<4;mi_++)                                               \
            af[mi_][kc_] = *(const s16x8*)(&AS[BUF][MH][aB[kc_] + mi_*1024]); } }while(0)
#define READ_BF(BUF,NH,DST) do{ _Pragma("unroll")                                \
    for(int kc_=0;kc_<2;kc_++){ _Pragma("unroll")                                \
        for(int nj_=0;nj_<2;nj_++)                                               \
            DST[nj_][kc_] = *(const s16x8*)(&BS[BUF][NH][bB[kc_] + nj_*1024]); } }while(0)
// kc-outer: dependent same-acc MFMAs 8 apart
#define MFMA16(BFR,MH,NH) do{ _Pragma("unroll")                                  \
    for(int kc_=0;kc_<2;kc_++){ _Pragma("unroll")                                \
        for(int mi_=0;mi_<4;mi_++){ _Pragma("unroll")                            \
            for(int nj_=0;nj_<2;nj_++)                                           \
                acc[(MH)*4+mi_][(NH)*2+nj_] =                                    \
                    __builtin_amdgcn_mfma_f32_16x16x32_bf16(                     \
                        af[mi_][kc_], BFR[nj_][kc_],                             \
                        acc[(MH)*4+mi_][(NH)*2+nj_], 0,0,0); } } }while(0)

#define STG_A0(BUF,OFF) do{ gl16(pA0[0]+(OFF), &AS[BUF][0][dE0]);                \
                            gl16(pA0[1]+(OFF), &AS[BUF][0][dE1]); }while(0)
#define STG_A1(BUF,OFF) do{ gl16(pA1[0]+(OFF), &AS[BUF][1][dE0]);                \
                            gl16(pA1[1]+(OFF), &AS[BUF][1][dE1]); }while(0)
#define STG_B0(BUF,OFF) do{ gl16(pB0[0]+(OFF), &BS[BUF][0][dE0]);                \
                            gl16(pB0[1]+(OFF), &BS[BUF][0][dE1]); }while(0)
#define STG_B1(BUF,OFF) do{ gl16(pB1[0]+(OFF), &BS[BUF][1][dE0]);                \
                            gl16(pB1[1]+(OFF), &BS[BUF][1][dE1]); }while(0)

#define TILE(BUF,O1,O2,GA1,GR)                                                   \
    do{                                                                          \
        /* P1 */                                                                 \
        if (GA1) STG_A1(BUF^1, O1);                                              \
        READ_AF(BUF,0); READ_BF(BUF,0,bf0);                                      \
        BAR(); LGKM0(); SCHED();                                                 \
        __builtin_amdgcn_s_setprio(1);  MFMA16(bf0,0,0);                         \
        __builtin_amdgcn_s_setprio(0);                                           \
        BAR(); SCHED();                                                          \
        /* P2 */                                                                 \
        if (GR) STG_A0(BUF,O2);                                                  \
        READ_BF(BUF,1,bf1);                                                      \
        BAR(); LGKM0(); SCHED();                                                 \
        __builtin_amdgcn_s_setprio(1);  MFMA16(bf1,0,1);                         \
        __builtin_amdgcn_s_setprio(0);                                           \
        BAR(); SCHED();                                                          \
        /* P3 */                                                                 \
        if (GR) STG_B0(BUF,O2);                                                  \
        READ_AF(BUF,1);                                                          \
        BAR(); LGKM0(); SCHED();                                                 \
        __builtin_amdgcn_s_setprio(1);  MFMA16(bf0,1,0);                         \
        __builtin_amdgcn_s_setprio(0);                                           \
        BAR(); SCHED();                                                          \
        /* P4 */                                                                 \
        if (GR){ STG_B1(BUF,O2); VM6(); } else { VM0(); }                        \
        BAR(); SCHED();                                                          \
        __builtin_amdgcn_s_setprio(1);  MFMA16(bf1,1,1);                         \
        __builtin_amdgcn_s_setprio(0);                                           \
        BAR(); SCHED();                                                          \
    }while(0)

    // prologue: tile0 {A0,B0,B1,A1}->buf0, tile1 {A0,B0,B1}->buf1
    STG_A0(0,0); STG_B0(0,0); STG_B1(0,0); STG_A1(0,0);
    STG_A0(1,64); STG_B0(1,64); STG_B1(1,64);
    VM6();                       // tile0 landed; {A0,B0,B1}(t1) in flight
    BAR(); SCHED();

    for(int g=0; g<NT; g+=2){
        const bool p2 = (g+2 < NT), p3 = (g+3 < NT);
        TILE(0, 64, 128, true, p2);
        TILE(1, 128, 192, p2, p3);
        pA0[0]+=128; pA0[1]+=128; pA1[0]+=128; pA1[1]+=128;
        pB0[0]+=128; pB0[1]+=128; pB1[0]+=128; pB1[1]+=128;
    }
#undef TILE
#undef STG_A0
#undef STG_A1
#undef STG_B0
#undef STG_B1
#undef MFMA16
#undef READ_BF
#undef READ_AF

    // epilogue: C write (row = rowbase+wm*128+mf*16+quad*4+r, col = colbase+wn*64+nf*16+l16)
    #pragma unroll
    for(int mf=0;mf<8;mf++)
        #pragma unroll
        for(int nf=0;nf<4;nf++)
            #pragma unroll
            for(int r=0;r<4;r++){
                size_t row = rowbase + wm*128 + mf*16 + quad*4 + r;
                size_t col = colbase + wn*64  + nf*16 + l16;
                store_c(C + row*(size_t)N + col, acc[mf][nf][r]);
            }
}

// ---------------- flash attention, S^T dataflow, pipelined staging ---------
// R12's counted-vmcnt K/V pipeline (KEPT; passed correctness), back on the
// qkv buffer (rs=QKVN).  Per tile kt: VM4+BAR (K landed; V in flight) ->
// QK^T -> BAR -> issue K(kt+1) -> softmax -> VM4/VM0 -> BAR -> PV -> BAR ->
// issue V(kt+1).  LDS 40KB -> 4 blocks/CU.
__global__ __launch_bounds__(256, 4) void k_attn(const bf16* __restrict__ qkv,
                                                 const bf16* __restrict__ vt,
                                                 bf16* __restrict__ y){
    __shared__ __align__(16) bf16 Ks[64*128];   // [key][d], 16 chunks/row, XOR swizzle
    __shared__ __align__(16) bf16 Vs[128*64];   // [d][key],  8 chunks/row, XOR swizzle
    __shared__ __align__(16) bf16 Ps[64*64];    // [q][key],  8 chunks/row, XOR swizzle
    const int id = blockIdx.x;
    const int x  = id & 7, g = id >> 3;
    const int qt = 7 - (g >> 5);
    const int bh = ((g & 31) << 3) | x;
    const int b = bh >> 4, h = bh & 15;
    const int tid = threadIdx.x, wave = tid>>6, lane = tid&63, quad = lane>>4, l16 = lane&15;
    const int qbase = qt*64;
    const size_t rs = QKVN;
    const bf16* Qg = qkv + ((size_t)b*SEQT)*rs + (size_t)h*HEADD;
    const bf16* Kg = Qg + DIM_C;
    const bf16* Vtbh = vt + ((size_t)bh*HEADD)*SEQT;

    s16x8 qf[4];
    const int qrow = qbase + wave*16 + l16;     // this lane's q row
    {
        #pragma unroll
        for(int kc=0;kc<4;kc++)
            qf[kc] = *(const s16x8*)(Qg + (size_t)qrow*rs + kc*32 + quad*8);
    }
    f32x4 acc_o[8];                              // O^T: d=dt*16+quad*4+r, q=l16
    #pragma unroll
    for(int dt=0;dt<8;dt++) acc_o[dt] = (f32x4)(0.f);
    float lsum = 0.f;
    const float C2 = 0.12751745f;   // (1/sqrt(128)) * log2(e)
    const int nkt = qt + 1;

    auto stageK = [&](int kb){
        #pragma unroll
        for(int i=0;i<4;i++){
            int base = wave*256 + i*64;
            int cc   = base + lane;
            int rk   = cc>>4, gk = (cc&15) ^ (rk&7);
            gl16(Kg + (size_t)(kb+rk)*rs + gk*8, &Ks[base*8]);
        }
    };
    auto stageV = [&](int kb){
        #pragma unroll
        for(int i=0;i<4;i++){
            int base = wave*256 + i*64;
            int cc   = base + lane;
            int rv   = cc>>3, gv = (cc&7) ^ (rv&7);
            gl16(Vtbh + (size_t)rv*SEQT + kb + gv*8, &Vs[base*8]);
        }
    };

    stageK(0); stageV(0);                       // prologue

    for(int kt=0; kt<nkt; kt++){
        const int kbase = kt*64;
        const bool diag = (kt == nkt-1);
        const bool more = (kt+1 < nkt);
        VM4(); BAR(); SCHED();                  // K(kt) landed everywhere
        // S^T = K Q^T: A = K rows (m=key), B = Q rows (n=q)
        f32x4 sacc[4];
        #pragma unroll
        for(int ni=0;ni<4;ni++) sacc[ni] = (f32x4)(0.f);
        __builtin_amdgcn_s_setprio(1);
        #pragma unroll
        for(int kc=0;kc<4;kc++){
            const int ch = kc*4 + quad;
            #pragma unroll
            for(int ni=0;ni<4;ni++){
                int r = ni*16 + l16;
                s16x8 kf = *(const s16x8*)(&Ks[r*128 + ((ch ^ (r&7))*8)]);
                sacc[ni] = __builtin_amdgcn_mfma_f32_16x16x32_bf16(kf, qf[kc], sacc[ni], 0,0,0);
            }
        }
        __builtin_amdgcn_s_setprio(0);
        SCHED(); BAR(); SCHED();                // Ks reads done (all waves)
        if (more) stageK(kbase+64);             // K(kt+1) issue, hidden by softmax
        // P^T = exp2(S^T*C2), causal mask -> 0; write wave-private Ps rows.
        {
            const int row = wave*16 + l16;
            const int r7  = row & 7;
            #pragma unroll
            for(int ni=0;ni<4;ni++){
                union { s16x4 v; bf16 hh[4]; } pk;
                #pragma unroll
                for(int rr=0;rr<4;rr++){
                    float e = exp2f(sacc[ni][rr]*C2);
                    if (diag){ int kcol = kbase + ni*16 + quad*4 + rr; if (kcol > qrow) e = 0.f; }
                    lsum += e;
                    pk.hh[rr] = __float2bfloat16(e);
                }
                int c = ni*2 + (quad>>1);            // 8-elt chunk index
                *(s16x4*)(&Ps[row*64 + ((c ^ r7)<<3) + ((quad&1)<<2)]) = pk.v;
            }
        }
        if (more){ VM4(); } else { VM0(); }     // V(kt) landed (leaves K(kt+1))
        BAR(); SCHED();
        // O^T += V^T P^T  (A = vf: m=d, k=key; B = pf: n=q, k=key)
        __builtin_amdgcn_s_setprio(1);
        #pragma unroll
        for(int kk=0;kk<2;kk++){
            int rw = wave*16 + l16;
            int c  = kk*4 + quad;
            s16x8 pf = *(const s16x8*)(&Ps[rw*64 + ((c ^ (rw&7))<<3)]);
            #pragma unroll
            for(int dt=0;dt<8;dt++){
                int r = dt*16 + l16;
                s16x8 vf = *(const s16x8*)(&Vs[r*64 + ((c ^ (r&7))<<3)]);
                acc_o[dt] = __builtin_amdgcn_mfma_f32_16x16x32_bf16(vf, pf, acc_o[dt], 0,0,0);
            }
        }
        __builtin_amdgcn_s_setprio(0);
        SCHED(); BAR(); SCHED();                // Vs reads done (all waves)
        if (more) stageV(kbase+64);             // V(kt+1) issue
    }
    lsum += __shfl_xor(lsum, 16, 64);
    lsum += __shfl_xor(lsum, 32, 64);
    float inv_l = 1.f/lsum;
    size_t base = ((size_t)(b*SEQT) + qrow)*DIM_C + (size_t)h*HEADD;
    #pragma unroll
    for(int dt=0;dt<8;dt++){
        union { s16x4 v; bf16 hh[4]; } o;
        #pragma unroll
        for(int rr=0;rr<4;rr++) o.hh[rr] = __float2bfloat16(acc_o[dt][rr]*inv_l);
        *(s16x4*)(y + base + dt*16 + quad*4) = o.v;
    }
}

extern "C" void kernel_launch(void* const* d_in, const int* in_sizes, int n_in,
                              void* d_out, int out_size, void* d_ws, size_t ws_size,
                              hipStream_t stream){
    const float* x    = (const float*)d_in[0];
    const float* Wqkv = (const float*)d_in[1];
    const float* Wout = (const float*)d_in[2];
    float* out = (float*)d_out;
    char* ws = (char*)d_ws;
    // ws layout (bytes). vt aliases xb: xb dead after GEMM1, vt written after.
    bf16* xb    = (bf16*)(ws + 0);            //  32 MB: 8192x2048 (dead after GEMM1)
    bf16* vt    = (bf16*)(ws + 0);            //  32 MB: [b][h][128][512]
    bf16* wqkvT = (bf16*)(ws + 33554432);     //  24 MB: 6144x2048
    bf16* woutT = (bf16*)(ws + 58720256);     //   8 MB: 2048x2048
    bf16* qkv   = (bf16*)(ws + 67108864);     //  96 MB: 8192x6144
    bf16* yb    = (bf16*)(ws + 167772160);    //  32 MB: 8192x2048
    // total 192 MB

    k_cvt<<<dim3(MROWS*DIM_C/8/256), 256, 0, stream>>>(x, xb, MROWS*DIM_C);
    dim3 tb(32,8);
    k_transpose_cvt<<<dim3(QKVN/32, DIM_C/32), tb, 0, stream>>>(Wqkv, wqkvT, DIM_C, QKVN);
    k_transpose_cvt<<<dim3(DIM_C/32, DIM_C/32), tb, 0, stream>>>(Wout, woutT, DIM_C, DIM_C);

    k_gemm256<bf16><<<dim3(QKVN/256, MROWS/256), 512, 0, stream>>>(xb, wqkvT, qkv, MROWS, QKVN, DIM_C);
    k_rope<<<dim3(NBATCH*SEQT*NHEADS*2*8/256), 256, 0, stream>>>(qkv);
    k_vtrans<<<dim3(SEQT/32, HEADD/32, NBATCH*NHEADS), tb, 0, stream>>>(qkv, vt);
    k_attn<<<dim3(SEQT/64 * NHEADS * NBATCH), 256, 0, stream>>>(qkv, vt, yb);
    k_gemm256<float><<<dim3(DIM_C/256, MROWS/256), 512, 0, stream>>>(yb, woutT, out, MROWS, DIM_C, DIM_C);
}